// Round 1
// baseline (1951.054 us; speedup 1.0000x reference)
//
#include <hip/hip_runtime.h>
#include <stdint.h>

// Problem constants (B=4, Fc=4, H=512, W=1024, M=12)
#define HW      524288        // H*W
#define NB      4
#define NM      12
#define NSEG    48            // B*M
#define NBIN    256
#define CHUNK   2048          // elements per wave-chunk in sort
#define CHUNKS_PER_SEG (HW / CHUNK)   // 256
#define SORT_ITERS     (CHUNK / 64)   // 32

// ---------------- helpers ----------------

__device__ inline float blockRedSum(float v) {
    __shared__ float tmp[4];
    int lane = threadIdx.x & 63, w = threadIdx.x >> 6;
    #pragma unroll
    for (int o = 32; o > 0; o >>= 1) v += __shfl_down(v, o);
    __syncthreads();                 // protect tmp from a previous call
    if (lane == 0) tmp[w] = v;
    __syncthreads();
    return tmp[0] + tmp[1] + tmp[2] + tmp[3];   // blocks are always 256 threads
}

__device__ inline uint32_t waveInclScan(uint32_t x, int lane) {
    #pragma unroll
    for (int o = 1; o < 64; o <<= 1) {
        uint32_t t = __shfl_up(x, o);
        if (lane >= o) x += t;
    }
    return x;
}

// match mask: lanes in my wave whose 8-bit digit equals mine
__device__ inline unsigned long long digitMatch(uint32_t d) {
    unsigned long long m = ~0ull;
    #pragma unroll
    for (int b = 0; b < 8; ++b) {
        unsigned long long bb = __ballot((d >> b) & 1);
        m &= ((d >> b) & 1) ? bb : ~bb;
    }
    return m;
}

// ---------------- phase 1: per-(b,m) sums ----------------
// acc[seg*4 + {0,1,2,3}] = {count, sum_row, sum_col, sum_sigma}
__global__ __launch_bounds__(256) void k_seg_sums(
        const float* __restrict__ feats, const int* __restrict__ masks,
        float* __restrict__ acc) {
    int seg = blockIdx.y;
    int b   = seg / NM;
    const int*   mp  = masks + (size_t)seg * HW;
    const float* sig = feats + ((size_t)b * 4 + 2) * HW;
    int tid = threadIdx.x;
    int start = blockIdx.x * (256 * 32);
    float c0 = 0.f, c1 = 0.f, c2 = 0.f, c3 = 0.f;
    for (int it = 0; it < 32; ++it) {
        int p = start + it * 256 + tid;
        int m = mp[p];
        if (m) {
            int r = p >> 10, c = p & 1023;
            c0 += 1.0f;
            c1 += (float)((double)r * (1.0 / 1023.0));
            c2 += (float)((double)c * (1.0 / 2047.0));
            c3 += sig[p];
        }
    }
    float r0 = blockRedSum(c0);
    float r1 = blockRedSum(c1);
    float r2 = blockRedSum(c2);
    float r3 = blockRedSum(c3);
    if (tid == 0) {
        atomicAdd(&acc[seg * 4 + 0], r0);
        atomicAdd(&acc[seg * 4 + 1], r1);
        atomicAdd(&acc[seg * 4 + 2], r2);
        atomicAdd(&acc[seg * 4 + 3], r3);
    }
}

// ---------------- phase 2: per-seg params ----------------
// params[seg*4 + {0,1,2,3}] = {c_row, c_col, s, exp(10 s)}; msum[seg] = count
__global__ __launch_bounds__(64) void k_params(
        const float* __restrict__ acc, float* __restrict__ params,
        float* __restrict__ msum) {
    int i = threadIdx.x;
    if (i < NSEG) {
        float cnt = acc[i * 4 + 0];
        float den = cnt + 1e-6f;
        float c0 = acc[i * 4 + 1] / den;
        float c1 = acc[i * 4 + 2] / den;
        float s  = acc[i * 4 + 3] / den;
        params[i * 4 + 0] = c0;
        params[i * 4 + 1] = c1;
        params[i * 4 + 2] = s;
        params[i * 4 + 3] = expf(s * 10.0f);
        msum[i] = cnt;
    }
}

// ---------------- phase 3: per-pixel main ----------------
// writes sort keys (inv = ~(((errbits)&~1)|gt)), accumulates var/seed sums
__global__ __launch_bounds__(256) void k_main(
        const float* __restrict__ feats, const int* __restrict__ masks,
        const float* __restrict__ params, uint32_t* __restrict__ keys,
        double* __restrict__ gacc) {
    int b = blockIdx.y;
    int tid = threadIdx.x;
    __shared__ float lp[NM * 4];
    if (tid < NM * 4) lp[tid] = params[b * NM * 4 + tid];
    __syncthreads();
    const float* f0 = feats + ((size_t)b * 4 + 0) * HW;
    const float* f1 = feats + ((size_t)b * 4 + 1) * HW;
    const float* f2 = feats + ((size_t)b * 4 + 2) * HW;
    const float* f3 = feats + ((size_t)b * 4 + 3) * HW;
    int start = blockIdx.x * (256 * 8);
    float vsum = 0.f, ssum = 0.f;
    for (int it = 0; it < 8; ++it) {
        int p = start + it * 256 + tid;
        int r = p >> 10, c = p & 1023;
        float a0 = f0[p], a1 = f1[p], sg = f2[p], a3 = f3[p];
        float se0 = copysignf(log1pf(fabsf(a0)), a0) + (float)((double)r * (1.0 / 1023.0));
        float se1 = copysignf(log1pf(fabsf(a1)), a1) + (float)((double)c * (1.0 / 2047.0));
        float smap = 1.0f / (1.0f + expf(-a3));
        for (int mi = 0; mi < NM; ++mi) {
            float c0 = lp[mi * 4 + 0], c1 = lp[mi * 4 + 1];
            float s  = lp[mi * 4 + 2], sx = lp[mi * 4 + 3];
            int m = masks[((size_t)(b * NM + mi)) * HW + p] != 0;
            float d0 = se0 - c0, d1 = se1 - c1;
            float dist = expf(-(d0 * d0 + d1 * d1) * sx);
            float dv = m ? (sg - s) : 0.0f;
            vsum += m ? dv * dv : s * s;
            float ds = smap - dist;
            ssum += m ? ds * ds : 0.0f;
            float e = m ? (2.0f - 2.0f * dist) : (2.0f * dist);
            uint32_t item = (__float_as_uint(e) & ~1u) | (uint32_t)m;
            keys[((size_t)(b * NM + mi)) * HW + p] = ~item;
        }
    }
    float vb = blockRedSum(vsum);
    float sb = blockRedSum(ssum);
    if (tid == 0) {
        atomicAdd(&gacc[0], (double)vb);
        atomicAdd(&gacc[1], (double)sb);
    }
}

// ---------------- phase 4: segmented LSD radix sort ----------------
// hist layout: [seg_local][chunk][bin]
__global__ __launch_bounds__(256) void k_hist(
        const uint32_t* __restrict__ src, uint32_t* __restrict__ hist, int shift) {
    __shared__ uint32_t wh[4][NBIN];
    int sy = blockIdx.y;
    int tid = threadIdx.x, lane = tid & 63, w = tid >> 6;
    #pragma unroll
    for (int k = 0; k < 4; ++k) wh[w][lane + k * 64] = 0;   // own wave region, no sync needed
    int chunk = blockIdx.x * 4 + w;
    const uint32_t* cp = src + (size_t)sy * HW + (size_t)chunk * CHUNK;
    for (int j = 0; j < SORT_ITERS; ++j) {
        uint32_t kv = cp[j * 64 + lane];
        uint32_t d = (kv >> shift) & 255u;
        unsigned long long mm = digitMatch(d);
        int rank = __popcll(mm & ((1ull << lane) - 1ull));
        if (rank == 0) wh[w][d] += (uint32_t)__popcll(mm);
    }
    uint32_t* hp = hist + ((size_t)sy * CHUNKS_PER_SEG + chunk) * NBIN;
    #pragma unroll
    for (int k = 0; k < 4; ++k) hp[lane + k * 64] = wh[w][lane + k * 64];
}

// per-segment scan: hist[chunk][bin] -> exclusive offsets in (bin-major, chunk-minor) order
__global__ __launch_bounds__(1024) void k_scan(uint32_t* __restrict__ hist) {
    __shared__ uint32_t bintot[NBIN];
    __shared__ uint32_t binbase[NBIN];
    int tid = threadIdx.x, lane = tid & 63, w = tid >> 6;   // 16 waves
    uint32_t* H = hist + (size_t)blockIdx.x * CHUNKS_PER_SEG * NBIN;
    for (int bi = 0; bi < 16; ++bi) {
        int b = w * 16 + bi;
        uint32_t carry = 0;
        for (int i = 0; i < CHUNKS_PER_SEG / 64; ++i) {
            int cidx = i * 64 + lane;
            uint32_t v = H[(size_t)cidx * NBIN + b];
            uint32_t x = waveInclScan(v, lane);
            H[(size_t)cidx * NBIN + b] = carry + x - v;
            carry += __shfl(x, 63);
        }
        if (lane == 0) bintot[b] = carry;
    }
    __syncthreads();
    if (w == 0) {
        uint32_t carry = 0;
        for (int i = 0; i < 4; ++i) {
            uint32_t v = bintot[i * 64 + lane];
            uint32_t x = waveInclScan(v, lane);
            binbase[i * 64 + lane] = carry + x - v;
            carry += __shfl(x, 63);
        }
    }
    __syncthreads();
    for (int bi = 0; bi < 16; ++bi) {
        int b = w * 16 + bi;
        uint32_t bb = binbase[b];
        for (int i = 0; i < 4; ++i) {
            int cidx = i * 64 + lane;
            H[(size_t)cidx * NBIN + b] += bb;
        }
    }
}

__global__ __launch_bounds__(256) void k_scatter(
        const uint32_t* __restrict__ src, uint32_t* __restrict__ dst,
        const uint32_t* __restrict__ hist, int shift) {
    __shared__ uint32_t woff[4][NBIN];
    int sy = blockIdx.y;
    int tid = threadIdx.x, lane = tid & 63, w = tid >> 6;
    int chunk = blockIdx.x * 4 + w;
    const uint32_t* hp = hist + ((size_t)sy * CHUNKS_PER_SEG + chunk) * NBIN;
    #pragma unroll
    for (int k = 0; k < 4; ++k) woff[w][lane + k * 64] = hp[lane + k * 64];
    const uint32_t* cp = src + (size_t)sy * HW + (size_t)chunk * CHUNK;
    uint32_t* dp = dst + (size_t)sy * HW;
    for (int j = 0; j < SORT_ITERS; ++j) {
        uint32_t kv = cp[j * 64 + lane];
        uint32_t d = (kv >> shift) & 255u;
        unsigned long long mm = digitMatch(d);
        int rank = __popcll(mm & ((1ull << lane) - 1ull));
        uint32_t base = woff[w][d];          // all same-digit lanes read same base
        dp[base + (uint32_t)rank] = kv;      // stable: lane order == memory order
        if (rank == 0) woff[w][d] = base + (uint32_t)__popcll(mm);  // leader bumps
    }
}

// ---------------- phase 5: lovasz sum over sorted keys ----------------
__global__ __launch_bounds__(256) void k_gtcount(
        const uint32_t* __restrict__ keysA, uint32_t* __restrict__ cnt) {
    int seg = blockIdx.y;
    size_t base = (size_t)seg * HW + (size_t)blockIdx.x * 4096 + (size_t)threadIdx.x * 16;
    const uint4* p = (const uint4*)(keysA + base);
    int s = 0;
    #pragma unroll
    for (int i = 0; i < 4; ++i) {
        uint4 v = p[i];
        s += (int)((~v.x & 1u) + (~v.y & 1u) + (~v.z & 1u) + (~v.w & 1u));
    }
    float r = blockRedSum((float)s);
    if (threadIdx.x == 0) cnt[seg * 128 + blockIdx.x] = (uint32_t)(r + 0.5f);
}

__global__ __launch_bounds__(128) void k_cntscan(
        const uint32_t* __restrict__ cnt, uint32_t* __restrict__ cntoff) {
    __shared__ uint32_t wt[2];
    int tid = threadIdx.x, lane = tid & 63, w = tid >> 6;
    uint32_t v = cnt[blockIdx.x * 128 + tid];
    uint32_t x = waveInclScan(v, lane);
    if (lane == 63) wt[w] = x;
    __syncthreads();
    uint32_t add = (w == 1) ? wt[0] : 0u;
    cntoff[blockIdx.x * 128 + tid] = add + x - v;
}

__global__ __launch_bounds__(256) void k_terms(
        const uint32_t* __restrict__ keysA, const uint32_t* __restrict__ cntoff,
        const float* __restrict__ msum, double* __restrict__ gacc) {
    __shared__ uint32_t wtot[4];
    int seg = blockIdx.y;
    float G = msum[seg];
    int tid = threadIdx.x, lane = tid & 63, w = tid >> 6;
    size_t base = (size_t)seg * HW + (size_t)blockIdx.x * 4096;
    const uint4* p = (const uint4*)(keysA + base + (size_t)tid * 16);
    uint32_t word[16];
    #pragma unroll
    for (int i = 0; i < 4; ++i) {
        uint4 v = p[i];
        word[i * 4 + 0] = v.x; word[i * 4 + 1] = v.y;
        word[i * 4 + 2] = v.z; word[i * 4 + 3] = v.w;
    }
    uint32_t gsum = 0;
    #pragma unroll
    for (int j = 0; j < 16; ++j) gsum += (~word[j]) & 1u;
    // block-exclusive scan of per-thread gt counts (order = tid-major = memory order)
    uint32_t x = waveInclScan(gsum, lane);
    if (lane == 63) wtot[w] = x;
    __syncthreads();
    uint32_t wpre = 0;
    for (int i = 0; i < w; ++i) wpre += wtot[i];
    uint32_t excl = wpre + x - gsum;

    int C = (int)(cntoff[seg * 128 + blockIdx.x] + excl);
    int i0 = blockIdx.x * 4096 + tid * 16;     // 0-indexed position of first element
    float acc = 0.f;
    #pragma unroll
    for (int j = 0; j < 16; ++j) {
        uint32_t item = ~word[j];
        int g = (int)(item & 1u);
        float e = __uint_as_float(item & ~1u);
        e = fmaxf(e, 0.0f);
        C += g;
        float fi = (float)(i0 + j + 1);
        float fC = (float)C;
        float Jc = 1.0f - (G - fC) / (G + fi - fC);
        float Jp;
        if (i0 + j == 0) {
            Jp = 0.0f;
        } else {
            float fim = fi - 1.0f;
            float fCp = fC - (float)g;
            Jp = 1.0f - (G - fCp) / (G + fim - fCp);
        }
        acc += e * (Jc - Jp);
    }
    float r = blockRedSum(acc);
    if (tid == 0) atomicAdd(&gacc[2], (double)r);
}

// ---------------- phase 6: combine ----------------
__global__ __launch_bounds__(64) void k_final(
        const double* __restrict__ gacc, float* __restrict__ out) {
    if (threadIdx.x == 0) {
        double denom = (double)NSEG * (double)HW;        // B*M*HW
        double var_loss  = gacc[0] / denom;
        double seed_loss = gacc[1] / denom;
        double inst_loss = gacc[2] / (double)NSEG;
        out[0] = (float)(1.0 * inst_loss + 0.01 * var_loss + 0.01 * seed_loss);
    }
}

// ---------------- host ----------------
extern "C" void kernel_launch(void* const* d_in, const int* in_sizes, int n_in,
                              void* d_out, int out_size, void* d_ws, size_t ws_size,
                              hipStream_t stream) {
    const float* feats = (const float*)d_in[0];
    const int*   masks = (const int*)d_in[1];
    float* out = (float*)d_out;

    uint8_t* base = (uint8_t*)d_ws;
    size_t off = 0;
    auto carve = [&](size_t bytes) -> void* {
        void* p = base + off;
        off += (bytes + 255) & ~(size_t)255;
        return p;
    };
    auto al = [](size_t x) { return (x + 255) & ~(size_t)255; };

    uint32_t* keysA = (uint32_t*)carve((size_t)NSEG * HW * 4);

    // pick sort group size by available workspace (ping-pong + hist are group-sized)
    size_t fixed_tail = al((size_t)NSEG * 16) + al((size_t)NSEG * 16) + al((size_t)NSEG * 4)
                      + al((size_t)NSEG * 128 * 4) * 2 + al(3 * 8);
    int G = 1;
    {
        const int cand[4] = {48, 12, 4, 1};
        for (int ci = 0; ci < 4; ++ci) {
            int g = cand[ci];
            size_t need = off + al((size_t)g * HW * 4)
                        + al((size_t)g * CHUNKS_PER_SEG * NBIN * 4) + fixed_tail;
            if (need <= ws_size) { G = g; break; }
        }
    }
    uint32_t* keysB = (uint32_t*)carve((size_t)G * HW * 4);
    uint32_t* hist  = (uint32_t*)carve((size_t)G * CHUNKS_PER_SEG * NBIN * 4);
    float* acc    = (float*)carve((size_t)NSEG * 16);
    float* params = (float*)carve((size_t)NSEG * 16);
    float* msum   = (float*)carve((size_t)NSEG * 4);
    uint32_t* cnt    = (uint32_t*)carve((size_t)NSEG * 128 * 4);
    uint32_t* cntoff = (uint32_t*)carve((size_t)NSEG * 128 * 4);
    double* gacc = (double*)carve(3 * 8);

    hipMemsetAsync(acc, 0, (size_t)NSEG * 16, stream);
    hipMemsetAsync(gacc, 0, 3 * 8, stream);

    k_seg_sums<<<dim3(64, NSEG), 256, 0, stream>>>(feats, masks, acc);
    k_params<<<1, 64, 0, stream>>>(acc, params, msum);
    k_main<<<dim3(256, NB), 256, 0, stream>>>(feats, masks, params, keysA, gacc);

    int nGroups = NSEG / G;
    for (int grp = 0; grp < nGroups; ++grp) {
        uint32_t* A = keysA + (size_t)grp * G * HW;
        dim3 gh(CHUNKS_PER_SEG / 4, G);
        // pass 0: A->B (bits 0..7)
        k_hist<<<gh, 256, 0, stream>>>(A, hist, 0);
        k_scan<<<G, 1024, 0, stream>>>(hist);
        k_scatter<<<gh, 256, 0, stream>>>(A, keysB, hist, 0);
        // pass 1: B->A (bits 8..15)
        k_hist<<<gh, 256, 0, stream>>>(keysB, hist, 8);
        k_scan<<<G, 1024, 0, stream>>>(hist);
        k_scatter<<<gh, 256, 0, stream>>>(keysB, A, hist, 8);
        // pass 2: A->B (bits 16..23)
        k_hist<<<gh, 256, 0, stream>>>(A, hist, 16);
        k_scan<<<G, 1024, 0, stream>>>(hist);
        k_scatter<<<gh, 256, 0, stream>>>(A, keysB, hist, 16);
        // pass 3: B->A (bits 24..31)
        k_hist<<<gh, 256, 0, stream>>>(keysB, hist, 24);
        k_scan<<<G, 1024, 0, stream>>>(hist);
        k_scatter<<<gh, 256, 0, stream>>>(keysB, A, hist, 24);
    }

    k_gtcount<<<dim3(128, NSEG), 256, 0, stream>>>(keysA, cnt);
    k_cntscan<<<NSEG, 128, 0, stream>>>(cnt, cntoff);
    k_terms<<<dim3(128, NSEG), 256, 0, stream>>>(keysA, cntoff, msum, gacc);
    k_final<<<1, 64, 0, stream>>>(gacc, out);
}